// Round 1
// baseline (234.388 us; speedup 1.0000x reference)
//
#include <hip/hip_runtime.h>

#define CCH 256
#define HH 200
#define WW 200
#define HWW (HH * WW)
#define PHB 7
#define PWB 7
#define NBINS 49

// ---------------------------------------------------------------------------
// Transpose (B, C, H*W) -> (B, H*W, C) so channel reads coalesce.
// H*W = 40000 and C = 256 are multiples of 32 -> no bounds checks.
// ---------------------------------------------------------------------------
__global__ __launch_bounds__(256) void transpose_kernel(
    const float* __restrict__ in, float* __restrict__ out) {
  __shared__ float tile[32][33];  // +1 pad: conflict-free transpose
  int b  = blockIdx.z;
  int p0 = blockIdx.x * 32;   // pixel tile
  int c0 = blockIdx.y * 32;   // channel tile
  int tx = threadIdx.x;       // 0..31
  int ty = threadIdx.y;       // 0..7
  const float* ip = in  + (size_t)b * CCH * HWW;
  float*       op = out + (size_t)b * HWW * CCH;
#pragma unroll
  for (int i = 0; i < 32; i += 8) {
    tile[ty + i][tx] = ip[(size_t)(c0 + ty + i) * HWW + (p0 + tx)];
  }
  __syncthreads();
#pragma unroll
  for (int i = 0; i < 32; i += 8) {
    op[(size_t)(p0 + ty + i) * CCH + (c0 + tx)] = tile[tx][ty + i];
  }
}

// ---------------------------------------------------------------------------
// RoI Align: one block per roi, thread = channel.
// TRANS=true  : feat is NHWC (transposed workspace) -> coalesced taps
// TRANS=false : feat is NCHW (fallback if ws too small)
// ---------------------------------------------------------------------------
template <bool TRANS>
__global__ __launch_bounds__(256) void roi_kernel(
    const float* __restrict__ feat, const float* __restrict__ rois,
    const int* __restrict__ sidx, float* __restrict__ out) {
  __shared__ float s_out[CCH * NBINS];  // 50176 B staging for coalesced write
  __shared__ int   s_yi[2][14];         // y0*W, y1*W per sample row
  __shared__ int   s_xi[2][14];         // x0, x1 per sample col
  __shared__ float s_lh_y[2][14];       // ly, hy
  __shared__ float s_lh_x[2][14];       // lx, hx
  __shared__ float s_vy[14];
  __shared__ float s_vx[14];

  const int n = blockIdx.x;
  const int c = threadIdx.x;

  const float x1 = rois[n * 4 + 0];
  const float y1 = rois[n * 4 + 1];
  const float x2 = rois[n * 4 + 2];
  const float y2 = rois[n * 4 + 3];
  const int   b  = sidx[n];
  const float roi_w = fmaxf(x2 - x1, 1.0f);
  const float roi_h = fmaxf(y2 - y1, 1.0f);
  // Use true division to match the reference bit pattern as closely as
  // possible (floor() boundary sensitivity).
  const float bin_w = roi_w / 7.0f;
  const float bin_h = roi_h / 7.0f;

  const int t = threadIdx.x;
  if (t < 14) {
    const float tt = ((float)t + 0.5f) * 0.5f;  // (i+0.5)/SR
    const float ys = y1 + tt * bin_h;
    s_vy[t] = (ys >= -1.0f && ys <= (float)HH) ? 1.0f : 0.0f;
    const float yc  = fminf(fmaxf(ys, 0.0f), (float)(HH - 1));
    const int   yy0 = (int)yc;  // yc >= 0 -> trunc == floor
    const int   yy1 = min(yy0 + 1, HH - 1);
    const float ly  = yc - (float)yy0;
    s_yi[0][t]   = yy0 * WW;
    s_yi[1][t]   = yy1 * WW;
    s_lh_y[0][t] = ly;
    s_lh_y[1][t] = 1.0f - ly;
  } else if (t < 28) {
    const int   i  = t - 14;
    const float tt = ((float)i + 0.5f) * 0.5f;
    const float xs = x1 + tt * bin_w;
    s_vx[i] = (xs >= -1.0f && xs <= (float)WW) ? 1.0f : 0.0f;
    const float xc  = fminf(fmaxf(xs, 0.0f), (float)(WW - 1));
    const int   xx0 = (int)xc;
    const int   xx1 = min(xx0 + 1, WW - 1);
    const float lx  = xc - (float)xx0;
    s_xi[0][i]   = xx0;
    s_xi[1][i]   = xx1;
    s_lh_x[0][i] = lx;
    s_lh_x[1][i] = 1.0f - lx;
  }
  __syncthreads();

  const float* Fb;
  if (TRANS) {
    Fb = feat + (size_t)b * HWW * CCH + c;       // NHWC: tap = Fb[(y*W+x)*C]
  } else {
    Fb = feat + ((size_t)b * CCH + c) * HWW;     // NCHW: tap = Fb[y*W+x]
  }

#pragma unroll 1
  for (int ph = 0; ph < PHB; ++ph) {
#pragma unroll
    for (int pw = 0; pw < PWB; ++pw) {
      float acc = 0.0f;
#pragma unroll
      for (int sy = 0; sy < 2; ++sy) {
        const int   iy  = ph * 2 + sy;
        const int   yr0 = s_yi[0][iy];
        const int   yr1 = s_yi[1][iy];
        const float ly  = s_lh_y[0][iy];
        const float hy  = s_lh_y[1][iy];
        const float vy  = s_vy[iy];
#pragma unroll
        for (int sx = 0; sx < 2; ++sx) {
          const int   ix  = pw * 2 + sx;
          const int   xx0 = s_xi[0][ix];
          const int   xx1 = s_xi[1][ix];
          const float lx  = s_lh_x[0][ix];
          const float hx  = s_lh_x[1][ix];
          const float m   = vy * s_vx[ix];
          float f00, f01, f10, f11;
          if (TRANS) {
            f00 = Fb[(size_t)(yr0 + xx0) * CCH];
            f01 = Fb[(size_t)(yr0 + xx1) * CCH];
            f10 = Fb[(size_t)(yr1 + xx0) * CCH];
            f11 = Fb[(size_t)(yr1 + xx1) * CCH];
          } else {
            f00 = Fb[yr0 + xx0];
            f01 = Fb[yr0 + xx1];
            f10 = Fb[yr1 + xx0];
            f11 = Fb[yr1 + xx1];
          }
          acc += m * (hy * (hx * f00 + lx * f01) + ly * (hx * f10 + lx * f11));
        }
      }
      s_out[c * NBINS + ph * PWB + pw] = acc * 0.25f;  // mean over 2x2 samples
    }
  }
  __syncthreads();

  // Coalesced contiguous write of out[n] (C*49 floats).
  float* on = out + (size_t)n * (CCH * NBINS);
  for (int i = threadIdx.x; i < CCH * NBINS; i += 256) on[i] = s_out[i];
}

extern "C" void kernel_launch(void* const* d_in, const int* in_sizes, int n_in,
                              void* d_out, int out_size, void* d_ws, size_t ws_size,
                              hipStream_t stream) {
  const float* features = (const float*)d_in[0];
  const float* rois     = (const float*)d_in[1];
  const int*   sidx     = (const int*)d_in[2];
  float*       out      = (float*)d_out;

  const int N = in_sizes[1] / 4;               // rois: (N,4)
  const int B = in_sizes[0] / (CCH * HWW);     // features: (B,C,H,W)

  const size_t need = (size_t)B * HWW * CCH * sizeof(float);
  if (ws_size >= need) {
    float* ft = (float*)d_ws;
    dim3 tgrid(HWW / 32, CCH / 32, B);
    transpose_kernel<<<tgrid, dim3(32, 8), 0, stream>>>(features, ft);
    roi_kernel<true><<<N, 256, 0, stream>>>(ft, rois, sidx, out);
  } else {
    roi_kernel<false><<<N, 256, 0, stream>>>(features, rois, sidx, out);
  }
}